// Round 5
// baseline (3048.715 us; speedup 1.0000x reference)
//
#include <hip/hip_runtime.h>

typedef unsigned short u16;
typedef unsigned int   u32;
typedef unsigned long long u64;
typedef __attribute__((ext_vector_type(8))) short bf16x8;
typedef __attribute__((ext_vector_type(4))) float f32x4;

#define MFMA16(a,b,c) __builtin_amdgcn_mfma_f32_16x16x32_bf16((a),(b),(c),0,0,0)

// model dims: B=64 S=256 L=16 CE=50 E=100 H=300 NCLS=50
#define NWG   19      // ceil(300/16) h-slice WGs per direction
#define HP    320     // padded hidden (K for recurrent MFMA)
#define GP    304     // per-gate padded width (19*16)
#define XGB   4096    // u16 per (t,j) xg block: [4 gates][16 u][64 b]
#define SLOTS 257     // h time slots (slot 0 = initial zero state)

// ---------------- workspace layout (bytes) ----------------
static const size_t OFF_XG  = 0;                              // bf16 [2][256][19][4096] (reused L0/L1)
static const size_t SZ_XG   = (size_t)2*256*NWG*XGB*2;
static const size_t OFF_H0  = OFF_XG + SZ_XG;                 // bf16 [2][257][64][320]
static const size_t SZ_HB   = (size_t)2*SLOTS*64*HP*2;
static const size_t OFF_H1  = OFF_H0 + SZ_HB;
static const size_t OFF_CF  = OFF_H1 + SZ_HB;                 // charfeat bf16 [16384][64]
static const size_t SZ_CF   = (size_t)16384*64*2;
static const size_t OFF_W0  = OFF_CF + SZ_CF;                 // W0p bf16 [2432][160]  (n-major)
static const size_t SZ_W0   = (size_t)2432*160*2;
static const size_t OFF_W1  = OFF_W0 + SZ_W0;                 // W1p bf16 [2432][640]
static const size_t SZ_W1   = (size_t)2432*640*2;
static const size_t OFF_WFC = OFF_W1 + SZ_W1;                 // Wfc bf16 [64][640]
static const size_t SZ_WFC  = (size_t)64*640*2;
static const size_t OFF_B0  = OFF_WFC + SZ_WFC;               // f32 [2432]
static const size_t OFF_B1  = OFF_B0 + 2432*4;                // f32 [2432]
static const size_t OFF_BFC = OFF_B1 + 2432*4;                // f32 [64]
static const size_t OFF_FL0 = OFF_BFC + 64*4;                 // u32 [2][256][19]
static const size_t SZ_FL   = (size_t)2*256*NWG*4;
static const size_t OFF_FL1 = OFF_FL0 + SZ_FL;
static const size_t OFF_DT  = OFF_FL1 + SZ_FL;                // u32 dtype-probe count
static const size_t WS_NEED = OFF_DT + 4;

// ---------------- helpers ----------------
__device__ __forceinline__ float bf2f(u16 u){ union{u32 i; float f;} v; v.i=(u32)u<<16; return v.f; }
__device__ __forceinline__ u16 f2bf(float f){ union{float f; u32 u;} v; v.f=f; u32 r=v.u+0x7fffu+((v.u>>16)&1u); return (u16)(r>>16); }
__device__ __forceinline__ float sigf(float x){ return __builtin_amdgcn_rcpf(1.f+__builtin_amdgcn_exp2f(-1.4426950408889634f*x)); }
__device__ __forceinline__ float tanhf_(float x){ return 2.f*__builtin_amdgcn_rcpf(1.f+__builtin_amdgcn_exp2f(-2.8853900817779268f*x))-1.f; }
// dtype-adaptive input loads (isf32 is wave-uniform)
__device__ __forceinline__ float ldf(const void* p, size_t i, bool f32){
  return f32 ? ((const float*)p)[i] : bf2f(((const u16*)p)[i]);
}
__device__ __forceinline__ u16 ldh(const void* p, size_t i, bool f32){
  return f32 ? f2bf(((const float*)p)[i]) : ((const u16*)p)[i];
}

// ---------------- dtype probe ----------------
__global__ __launch_bounds__(256,1) void k_detect(const u16* __restrict__ probe, u32* __restrict__ cnt)
{
  int c = 0;
  for (int i = threadIdx.x; i < 65536; i += 256) {
    u16 v = probe[i];
    if (((v >> 7) & 0xFF) == 0xFF) ++c;
  }
  if (c) atomicAdd(cnt, (u32)c);
}

// ---------------- weight/bias repack ----------------
__global__ __launch_bounds__(256,4) void k_prep(
    const void* __restrict__ b0_Wih, const void* __restrict__ b0_bih, const void* __restrict__ b0_bhh,
    const void* __restrict__ b1_Wih, const void* __restrict__ b1_bih, const void* __restrict__ b1_bhh,
    const void* __restrict__ fcW,    const void* __restrict__ fcb,
    u16* __restrict__ W0p, u16* __restrict__ W1p, u16* __restrict__ Wfc,
    float* __restrict__ bias0, float* __restrict__ bias1, float* __restrict__ biasfc,
    const u32* __restrict__ dtf)
{
  const bool isf32 = (*dtf >= 8u);
  const int T0 = 2432*160, T1 = 2432*640, T2 = 64*640;
  const int total = T0 + T1 + T2 + 2432 + 2432 + 64;
  for (int i = blockIdx.x*256 + threadIdx.x; i < total; i += gridDim.x*256) {
    int x = i;
    if (x < T0) {
      int n = x/160, k = x%160;
      int dir = n/1216, cc = n%1216, g = cc/GP, uu = cc%GP;
      W0p[x] = (uu<300 && k<150) ? ldh(b0_Wih, ((size_t)dir*1200 + g*300 + uu)*150 + k, isf32) : (u16)0;
      continue;
    }
    x -= T0;
    if (x < T1) {
      int n = x/640, k = x%640;
      int dir = n/1216, cc = n%1216, g = cc/GP, uu = cc%GP;
      int part = (k>=320), ui = k - part*320;
      W1p[x] = (uu<300 && ui<300) ? ldh(b1_Wih, ((size_t)dir*1200 + g*300 + uu)*600 + part*300 + ui, isf32) : (u16)0;
      continue;
    }
    x -= T1;
    if (x < T2) {
      int n = x/640, k = x%640;
      int part = (k>=320), ui = k - part*320;
      Wfc[x] = (n<50 && ui<300) ? ldh(fcW, (size_t)n*600 + part*300 + ui, isf32) : (u16)0;
      continue;
    }
    x -= T2;
    if (x < 2432) {
      int dir = x/1216, cc = x%1216, g = cc/GP, uu = cc%GP;
      bias0[x] = (uu<300) ? ldf(b0_bih, dir*1200+g*300+uu, isf32) + ldf(b0_bhh, dir*1200+g*300+uu, isf32) : 0.f;
      continue;
    }
    x -= 2432;
    if (x < 2432) {
      int dir = x/1216, cc = x%1216, g = cc/GP, uu = cc%GP;
      bias1[x] = (uu<300) ? ldf(b1_bih, dir*1200+g*300+uu, isf32) + ldf(b1_bhh, dir*1200+g*300+uu, isf32) : 0.f;
      continue;
    }
    x -= 2432;
    biasfc[x] = (x<50) ? ldf(fcb, x, isf32) : 0.f;
  }
}

// ---------------- char LSTM (2 layers, L=16), 64 seqs/WG ----------------
__global__ __launch_bounds__(256,1) void k_char(
    const int* __restrict__ char_ids, const void* __restrict__ cemb,
    const void* __restrict__ cWih, const void* __restrict__ cWhh,
    const void* __restrict__ cbih, const void* __restrict__ cbhh,
    u16* __restrict__ charfeat, const u32* __restrict__ dtf)
{
  __shared__ u16 emb[128][64];   // char embed table, cols 50-63 zero
  __shared__ int ids[16][64];    // [t][seq]
  __shared__ u16 h0s[64][64];
  __shared__ u16 h1s[64][64];
  const bool isf32 = (*dtf >= 8u);
  const int tid = threadIdx.x;
  const int g0  = blockIdx.x * 64;

  for (int e = tid; e < 128*64; e += 256) {
    int row = e>>6, col = e&63;
    (&emb[0][0])[e] = (col<50) ? ldh(cemb, row*50 + col, isf32) : (u16)0;
  }
  for (int e = tid; e < 1024; e += 256) ids[e&15][e>>4] = char_ids[(size_t)g0*16 + e];
  for (int e = tid; e < 4096; e += 256) { (&h0s[0][0])[e] = 0; (&h1s[0][0])[e] = 0; }
  __syncthreads();

  const int w = tid>>6, lane = tid&63, quad = lane>>4, lcol = lane&15;
  const int u = w*16 + lcol;                       // owned unit col

  bf16x8 Wf[2][4][4];
  #pragma unroll
  for (int l=0; l<2; ++l)
    #pragma unroll
    for (int g=0; g<4; ++g)
      #pragma unroll
      for (int kt=0; kt<4; ++kt) {
        union { bf16x8 v; u16 h[8]; } t8;
        #pragma unroll
        for (int q=0; q<8; ++q) {
          int k = kt*32 + quad*8 + q;
          u16 val = 0;
          if (u < 50) {
            if (k < 50)                  val = ldh(cWih, l*10000 + (g*50+u)*50 + k, isf32);
            else if (k >= 64 && k < 114) val = ldh(cWhh, l*10000 + (g*50+u)*50 + (k-64), isf32);
          }
          t8.h[q] = val;
        }
        Wf[l][g][kt] = t8.v;
      }
  float bs[2][4];
  #pragma unroll
  for (int l=0; l<2; ++l)
    #pragma unroll
    for (int g=0; g<4; ++g)
      bs[l][g] = (u<50) ? ldf(cbih, l*200+g*50+u, isf32) + ldf(cbhh, l*200+g*50+u, isf32) : 0.f;

  float c0[4][4] = {}; float c1[4][4] = {};
  float h0n[4][4], h1n[4][4];

  for (int t=0; t<16; ++t) {
    // layer 0
    #pragma unroll
    for (int m=0; m<4; ++m) {
      f32x4 acc[4];
      #pragma unroll
      for (int g=0; g<4; ++g) acc[g] = (f32x4){bs[0][g], bs[0][g], bs[0][g], bs[0][g]};
      #pragma unroll
      for (int kt=0; kt<4; ++kt) {
        bf16x8 a;
        if (kt < 2) { int id = ids[t][m*16+lcol]; a = *(const bf16x8*)&emb[id][kt*32 + quad*8]; }
        else        { a = *(const bf16x8*)&h0s[m*16+lcol][(kt-2)*32 + quad*8]; }
        #pragma unroll
        for (int g=0; g<4; ++g) acc[g] = MFMA16(a, Wf[0][g][kt], acc[g]);
      }
      #pragma unroll
      for (int r=0; r<4; ++r) {
        float cn = sigf(acc[1][r])*c0[m][r] + sigf(acc[0][r])*tanhf_(acc[2][r]);
        c0[m][r] = cn;
        h0n[m][r] = sigf(acc[3][r]) * tanhf_(cn);
      }
    }
    __syncthreads();
    #pragma unroll
    for (int m=0; m<4; ++m)
      #pragma unroll
      for (int r=0; r<4; ++r) h0s[m*16 + quad*4 + r][u] = f2bf(h0n[m][r]);
    __syncthreads();
    // layer 1 (x = h0_t)
    #pragma unroll
    for (int m=0; m<4; ++m) {
      f32x4 acc[4];
      #pragma unroll
      for (int g=0; g<4; ++g) acc[g] = (f32x4){bs[1][g], bs[1][g], bs[1][g], bs[1][g]};
      #pragma unroll
      for (int kt=0; kt<4; ++kt) {
        bf16x8 a = (kt<2) ? *(const bf16x8*)&h0s[m*16+lcol][kt*32 + quad*8]
                          : *(const bf16x8*)&h1s[m*16+lcol][(kt-2)*32 + quad*8];
        #pragma unroll
        for (int g=0; g<4; ++g) acc[g] = MFMA16(a, Wf[1][g][kt], acc[g]);
      }
      #pragma unroll
      for (int r=0; r<4; ++r) {
        float cn = sigf(acc[1][r])*c1[m][r] + sigf(acc[0][r])*tanhf_(acc[2][r]);
        c1[m][r] = cn;
        h1n[m][r] = sigf(acc[3][r]) * tanhf_(cn);
      }
    }
    __syncthreads();
    #pragma unroll
    for (int m=0; m<4; ++m)
      #pragma unroll
      for (int r=0; r<4; ++r) h1s[m*16 + quad*4 + r][u] = f2bf(h1n[m][r]);
    __syncthreads();
  }
  for (int e = tid; e < 4096; e += 256)
    charfeat[(size_t)(g0 + (e>>6))*64 + (e&63)] = (&h1s[0][0])[e];
}

// xg epilogue addressing: n -> (dir, gate, slice j, unit uc); row -> (t, b)
__device__ __forceinline__ size_t xg_addr(int n, int row){
  int dir = n/1216, cc = n%1216, g = cc/GP, cg = cc%GP, jj = cg>>4, uc = cg&15;
  int t = row>>6, b = row&63;
  return (((size_t)dir*256 + t)*NWG + jj)*XGB + (g*16 + uc)*64 + b;
}

// ---------------- L0 input projection: xg = [emb|char] @ W0p^T + bias ----------------
__global__ __launch_bounds__(256,2) void k_proj0(
    const int* __restrict__ word_ids, const void* __restrict__ wemb,
    const u16* __restrict__ charfeat, const u16* __restrict__ W0p,
    const float* __restrict__ bias0, u16* __restrict__ xg, const u32* __restrict__ dtf)
{
  __shared__ u16 As[64][160];
  __shared__ u16 Bst[64][160];
  const bool isf32 = (*dtf >= 8u);
  const int tid = threadIdx.x;
  const int r0 = blockIdx.x*64, n0 = blockIdx.y*64;
  u32* Asu = (u32*)&As[0][0];
  u32* Bsu = (u32*)&Bst[0][0];
  for (int e = tid; e < 64*80; e += 256) {
    int rr = e/80, cu = e%80;
    int r = r0 + rr, t = r>>6, b = r&63;
    u32 v;
    if (cu < 50) {
      int wid = word_ids[b*256 + t];
      if (isf32) {
        const float* wf = (const float*)wemb;
        v = (u32)f2bf(wf[(size_t)wid*100 + cu*2]) | ((u32)f2bf(wf[(size_t)wid*100 + cu*2 + 1]) << 16);
      } else {
        v = ((const u32*)wemb)[(size_t)wid*50 + cu];
      }
    }
    else if (cu < 75) { v = ((const u32*)charfeat)[(size_t)r*32 + (cu-50)]; }
    else              v = 0;
    Asu[rr*80 + cu] = v;
  }
  for (int e = tid; e < 64*80; e += 256) {
    int n = e/80, cu = e%80;
    Bsu[n*80 + cu] = ((const u32*)W0p)[(size_t)(n0+n)*80 + cu];
  }
  __syncthreads();
  const int w = tid>>6, lane = tid&63, quad = lane>>4, lcol = lane&15;
  f32x4 acc[4] = {};
  #pragma unroll
  for (int kt=0; kt<5; ++kt) {
    bf16x8 a = *(const bf16x8*)&As[w*16+lcol][kt*32 + quad*8];
    #pragma unroll
    for (int nt=0; nt<4; ++nt) {
      bf16x8 bb = *(const bf16x8*)&Bst[nt*16+lcol][kt*32 + quad*8];
      acc[nt] = MFMA16(a, bb, acc[nt]);
    }
  }
  #pragma unroll
  for (int nt=0; nt<4; ++nt) {
    int n = n0 + nt*16 + lcol;
    float bia = bias0[n];
    #pragma unroll
    for (int r=0; r<4; ++r) {
      int row = r0 + w*16 + quad*4 + r;
      xg[xg_addr(n, row)] = f2bf(acc[nt][r] + bia);
    }
  }
}

// ---------------- L1 input projection: xg = [h0_fwd|h0_rev] @ W1p^T + bias ----------------
__global__ __launch_bounds__(256,2) void k_proj1(
    const u16* __restrict__ Hbuf, const u16* __restrict__ W1p,
    const float* __restrict__ bias1, u16* __restrict__ xg)
{
  __shared__ u16 As[64][128];
  __shared__ u16 Bst[64][128];
  const int tid = threadIdx.x;
  const int r0 = blockIdx.x*64, n0 = blockIdx.y*64;
  const u32* Hu = (const u32*)Hbuf;
  const u32* Wu = (const u32*)W1p;
  u32* Asu = (u32*)&As[0][0];
  u32* Bsu = (u32*)&Bst[0][0];
  const int w = tid>>6, lane = tid&63, quad = lane>>4, lcol = lane&15;
  f32x4 acc[4] = {};
  for (int ch=0; ch<5; ++ch) {
    __syncthreads();
    for (int e = tid; e < 4096; e += 256) {
      int rr = e>>6, cu = e&63;
      int r = r0 + rr, t = r>>6, b = r&63;
      int kk = ch*128 + cu*2;
      int part = (kk>=320), off = kk - part*320;
      Asu[e] = Hu[(((size_t)part*SLOTS + (part ? 256-t : t+1))*64 + b)*160 + (off>>1)];
    }
    for (int e = tid; e < 4096; e += 256) {
      int n = e>>6, cu = e&63;
      Bsu[e] = Wu[(size_t)(n0+n)*320 + ch*64 + cu];
    }
    __syncthreads();
    #pragma unroll
    for (int kt=0; kt<4; ++kt) {
      bf16x8 a = *(const bf16x8*)&As[w*16+lcol][kt*32 + quad*8];
      #pragma unroll
      for (int nt=0; nt<4; ++nt) {
        bf16x8 bb = *(const bf16x8*)&Bst[nt*16+lcol][kt*32 + quad*8];
        acc[nt] = MFMA16(a, bb, acc[nt]);
      }
    }
  }
  #pragma unroll
  for (int nt=0; nt<4; ++nt) {
    int n = n0 + nt*16 + lcol;
    float bia = bias1[n];
    #pragma unroll
    for (int r=0; r<4; ++r) {
      int row = r0 + w*16 + quad*4 + r;
      xg[xg_addr(n, row)] = f2bf(acc[nt][r] + bia);
    }
  }
}

// ---------------- recurrent scan: barrier-free, per-wave flag signaling ----------------
// flags[d][t][j]: incremented once per wave (4 waves/WG) after its h stores for slot t+1
// are vmcnt-drained. Consumers poll 19 flags (lanes 0..18 ONLY issue loads; lanes 19+
// contribute true) with s_sleep backoff to avoid an IC contention storm.
__global__ __launch_bounds__(256,1) void k_scan(
    const u16* __restrict__ xg, const void* __restrict__ Whh,
    u16* __restrict__ Hbuf, u32* __restrict__ flags, const u32* __restrict__ dtf)
{
  const bool isf32 = (*dtf >= 8u);
  const int bx = blockIdx.x;
  const int d = bx / NWG, j = bx % NWG;
  const int tid = threadIdx.x;
  const int w = tid>>6, lane = tid&63, quad = lane>>4, lcol = lane&15;
  const int u = j*16 + lcol;                      // owned unit col (n)
  const int brow = w*16;                          // M-tile batch base

  bf16x8 Bf[4][10];
  #pragma unroll
  for (int g=0; g<4; ++g)
    #pragma unroll
    for (int kt=0; kt<10; ++kt) {
      union { bf16x8 v; u16 h[8]; } t8;
      #pragma unroll
      for (int q=0; q<8; ++q) {
        int k = kt*32 + quad*8 + q;
        t8.h[q] = (u < 300 && k < 300) ? ldh(Whh, ((size_t)d*1200 + g*300 + u)*300 + k, isf32) : (u16)0;
      }
      Bf[g][kt] = t8.v;
    }

  float c[4] = {0.f,0.f,0.f,0.f};
  u32* flg = flags + (size_t)d*256*NWG;           // [t][19]

  for (int t=0; t<256; ++t) {
    const int tt = d ? (255 - t) : t;
    // prefetch xg for this step (independent of h) — in flight during the poll
    const volatile u64* xp = (const volatile u64*)(xg + (((size_t)d*256 + tt)*NWG + j)*XGB);
    u64 xq[4];
    #pragma unroll
    for (int g=0; g<4; ++g)
      xq[g] = xp[((g*16 + lcol)*64 + brow + quad*4) >> 2];

    if (t > 0) {
      const u32* f = flg + (t-1)*NWG;
      while (true) {
        u32 v = 4u;
        if (lane < NWG)     // exec-masked: lanes 19..63 issue NO load
          v = __hip_atomic_load(f + lane, __ATOMIC_RELAXED, __HIP_MEMORY_SCOPE_AGENT);
        if (__ballot(v >= 4u) == ~0ull) break;
        __builtin_amdgcn_s_sleep(2);
      }
      asm volatile("" ::: "memory");   // no hoisting h loads above the poll
    }

    f32x4 acc[4];
    #pragma unroll
    for (int g=0; g<4; ++g) {
      union { u64 q; u16 h[4]; } t4; t4.q = xq[g];
      #pragma unroll
      for (int r=0; r<4; ++r) acc[g][r] = bf2f(t4.h[r]);
    }
    #pragma unroll
    for (int kt=0; kt<10; ++kt) {
      size_t base = (((size_t)d*SLOTS + t)*64 + (brow + lcol))*HP + kt*32 + quad*8;
      union { bf16x8 v; u64 q[2]; } a;
      a.q[0] = __hip_atomic_load((u64*)(Hbuf + base),     __ATOMIC_RELAXED, __HIP_MEMORY_SCOPE_AGENT);
      a.q[1] = __hip_atomic_load((u64*)(Hbuf + base + 4), __ATOMIC_RELAXED, __HIP_MEMORY_SCOPE_AGENT);
      #pragma unroll
      for (int g=0; g<4; ++g) acc[g] = MFMA16(a.v, Bf[g][kt], acc[g]);
    }
    #pragma unroll
    for (int r=0; r<4; ++r) {
      float cn = sigf(acc[1][r])*c[r] + sigf(acc[0][r])*tanhf_(acc[2][r]);
      c[r] = cn;
      float h = sigf(acc[3][r]) * tanhf_(cn);
      u32 mine = (u32)f2bf(h);
      u32 other = (u32)__shfl_xor((int)mine, 1, 64);
      if ((lcol & 1) == 0) {
        u32 word = mine | (other << 16);
        int b = brow + quad*4 + r;
        size_t e = (((size_t)d*SLOTS + (t+1))*64 + b)*HP + j*16 + lcol;
        __hip_atomic_store((u32*)(Hbuf + e), word, __ATOMIC_RELAXED, __HIP_MEMORY_SCOPE_AGENT);
      }
    }
    asm volatile("s_waitcnt vmcnt(0)" ::: "memory");  // this wave's h stores are globally visible
    if (lane == 0)
      __hip_atomic_fetch_add(flg + t*NWG + j, 1u, __ATOMIC_RELAXED, __HIP_MEMORY_SCOPE_AGENT);
  }
}

// ---------------- FC + log_softmax ----------------
__global__ __launch_bounds__(256,2) void k_fc(
    const u16* __restrict__ Hbuf, const u16* __restrict__ Wfc,
    const float* __restrict__ biasfc, void* __restrict__ outv, const u32* __restrict__ dtf)
{
  __shared__ u16 As[64][128];
  __shared__ u16 Bst[64][128];
  const bool isf32 = (*dtf >= 8u);
  const int tid = threadIdx.x;
  const int r0 = blockIdx.x*64;
  const u32* Hu = (const u32*)Hbuf;
  const u32* Wu = (const u32*)Wfc;
  u32* Asu = (u32*)&As[0][0];
  u32* Bsu = (u32*)&Bst[0][0];
  const int w = tid>>6, lane = tid&63, quad = lane>>4, lcol = lane&15;
  f32x4 acc[4] = {};
  for (int ch=0; ch<5; ++ch) {
    __syncthreads();
    for (int e = tid; e < 4096; e += 256) {
      int rr = e>>6, cu = e&63;
      int r = r0 + rr, t = r>>6, b = r&63;
      int kk = ch*128 + cu*2;
      int part = (kk>=320), off = kk - part*320;
      Asu[e] = Hu[(((size_t)part*SLOTS + (part ? 256-t : t+1))*64 + b)*160 + (off>>1)];
    }
    for (int e = tid; e < 4096; e += 256) {
      int n = e>>6, cu = e&63;
      Bsu[e] = Wu[(size_t)n*320 + ch*64 + cu];
    }
    __syncthreads();
    #pragma unroll
    for (int kt=0; kt<4; ++kt) {
      bf16x8 a = *(const bf16x8*)&As[w*16+lcol][kt*32 + quad*8];
      #pragma unroll
      for (int nt=0; nt<4; ++nt) {
        bf16x8 bb = *(const bf16x8*)&Bst[nt*16+lcol][kt*32 + quad*8];
        acc[nt] = MFMA16(a, bb, acc[nt]);
      }
    }
  }
  float vals[4][4];
  #pragma unroll
  for (int nt=0; nt<4; ++nt) {
    int cc = nt*16 + lcol;
    float bia = biasfc[cc];
    #pragma unroll
    for (int r=0; r<4; ++r) vals[nt][r] = (cc < 50) ? (acc[nt][r] + bia) : -3.0e38f;
  }
  float lz[4];
  #pragma unroll
  for (int r=0; r<4; ++r) {
    float m = fmaxf(fmaxf(vals[0][r], vals[1][r]), fmaxf(vals[2][r], vals[3][r]));
    #pragma unroll
    for (int dd=1; dd<16; dd<<=1) m = fmaxf(m, __shfl_xor(m, dd, 64));
    float s = 0.f;
    #pragma unroll
    for (int nt=0; nt<4; ++nt) s += __builtin_amdgcn_exp2f((vals[nt][r]-m)*1.4426950408889634f);
    #pragma unroll
    for (int dd=1; dd<16; dd<<=1) s += __shfl_xor(s, dd, 64);
    lz[r] = m + __builtin_amdgcn_logf(s)*0.6931471805599453f;
  }
  #pragma unroll
  for (int nt=0; nt<4; ++nt) {
    int cc = nt*16 + lcol;
    if (cc < 50) {
      #pragma unroll
      for (int r=0; r<4; ++r) {
        int row = r0 + w*16 + quad*4 + r;
        int t = row>>6, b = row&63;
        size_t idx = ((size_t)b*256 + t)*50 + cc;
        float v = vals[nt][r] - lz[r];
        if (isf32) ((float*)outv)[idx] = v;
        else       ((u16*)outv)[idx] = f2bf(v);
      }
    }
  }
}

// ---------------- launch ----------------
extern "C" void kernel_launch(void* const* d_in, const int* in_sizes, int n_in,
                              void* d_out, int out_size, void* d_ws, size_t ws_size,
                              hipStream_t stream) {
  (void)in_sizes; (void)n_in; (void)out_size;
  if (ws_size < WS_NEED) return;

  const int* word_ids = (const int*)d_in[0];
  const int* char_ids = (const int*)d_in[1];
  const void* wemb   = d_in[2];
  const void* cemb   = d_in[3];
  const void* cWih   = d_in[4];
  const void* cWhh   = d_in[5];
  const void* cbih   = d_in[6];
  const void* cbhh   = d_in[7];
  const void* b0_Wih = d_in[8];
  const void* b0_Whh = d_in[9];
  const void* b0_bih = d_in[10];
  const void* b0_bhh = d_in[11];
  const void* b1_Wih = d_in[12];
  const void* b1_Whh = d_in[13];
  const void* b1_bih = d_in[14];
  const void* b1_bhh = d_in[15];
  const void* fcW    = d_in[16];
  const void* fcb    = d_in[17];

  char* ws = (char*)d_ws;
  u16*   xg   = (u16*)(ws + OFF_XG);
  u16*   H0   = (u16*)(ws + OFF_H0);
  u16*   H1   = (u16*)(ws + OFF_H1);
  u16*   cf   = (u16*)(ws + OFF_CF);
  u16*   W0p  = (u16*)(ws + OFF_W0);
  u16*   W1p  = (u16*)(ws + OFF_W1);
  u16*   Wfc  = (u16*)(ws + OFF_WFC);
  float* bia0 = (float*)(ws + OFF_B0);
  float* bia1 = (float*)(ws + OFF_B1);
  float* biaf = (float*)(ws + OFF_BFC);
  u32*   fl0  = (u32*)(ws + OFF_FL0);
  u32*   fl1  = (u32*)(ws + OFF_FL1);
  u32*   dtf  = (u32*)(ws + OFF_DT);

  // zero: initial h slots (slot 0, both dirs, both layers) + step flags + dtype count
  hipMemsetAsync(H0,                       0, (size_t)64*HP*2, stream);
  hipMemsetAsync(H0 + (size_t)SLOTS*64*HP, 0, (size_t)64*HP*2, stream);
  hipMemsetAsync(H1,                       0, (size_t)64*HP*2, stream);
  hipMemsetAsync(H1 + (size_t)SLOTS*64*HP, 0, (size_t)64*HP*2, stream);
  hipMemsetAsync(ws + OFF_FL0, 0, 2*SZ_FL + 4, stream);

  k_detect<<<1, 256, 0, stream>>>((const u16*)wemb, dtf);
  k_prep<<<7780, 256, 0, stream>>>(b0_Wih, b0_bih, b0_bhh, b1_Wih, b1_bih, b1_bhh,
                                   fcW, fcb, W0p, W1p, Wfc, bia0, bia1, biaf, dtf);
  k_char<<<256, 256, 0, stream>>>(char_ids, cemb, cWih, cWhh, cbih, cbhh, cf, dtf);
  k_proj0<<<dim3(256,38), 256, 0, stream>>>(word_ids, wemb, cf, W0p, bia0, xg, dtf);
  k_scan<<<2*NWG, 256, 0, stream>>>(xg, b0_Whh, H0, fl0, dtf);
  k_proj1<<<dim3(256,38), 256, 0, stream>>>(H0, W1p, bia1, xg);
  k_scan<<<2*NWG, 256, 0, stream>>>(xg, b1_Whh, H1, fl1, dtf);
  k_fc<<<256, 256, 0, stream>>>(H1, Wfc, biaf, d_out, dtf);
}

// Round 6
// 2909.971 us; speedup vs baseline: 1.0477x; 1.0477x over previous
//
#include <hip/hip_runtime.h>

typedef unsigned short u16;
typedef unsigned int   u32;
typedef unsigned long long u64;
typedef __attribute__((ext_vector_type(8))) short bf16x8;
typedef __attribute__((ext_vector_type(4))) float f32x4;

#define MFMA16(a,b,c) __builtin_amdgcn_mfma_f32_16x16x32_bf16((a),(b),(c),0,0,0)

// model dims: B=64 S=256 L=16 CE=50 E=100 H=300 NCLS=50
#define NWG   19      // ceil(300/16) h-slice WGs per direction
#define HP    320     // padded hidden (K for recurrent MFMA)
#define GP    304     // per-gate padded width (19*16)
#define XGB   4096    // u16 per (t,j) xg block: [4 gates][16 u][64 b]
#define SLOTS 257     // h time slots (slot 0 = initial zero state)

// ---------------- workspace layout (bytes) ----------------
static const size_t OFF_XG  = 0;                              // bf16 [2][256][19][4096] (reused L0/L1)
static const size_t SZ_XG   = (size_t)2*256*NWG*XGB*2;
static const size_t OFF_H0  = OFF_XG + SZ_XG;                 // bf16 [2][257][64][320]
static const size_t SZ_HB   = (size_t)2*SLOTS*64*HP*2;
static const size_t OFF_H1  = OFF_H0 + SZ_HB;
static const size_t OFF_CF  = OFF_H1 + SZ_HB;                 // charfeat bf16 [16384][64]
static const size_t SZ_CF   = (size_t)16384*64*2;
static const size_t OFF_W0  = OFF_CF + SZ_CF;                 // W0p bf16 [2432][160]  (n-major)
static const size_t SZ_W0   = (size_t)2432*160*2;
static const size_t OFF_W1  = OFF_W0 + SZ_W0;                 // W1p bf16 [2432][640]
static const size_t SZ_W1   = (size_t)2432*640*2;
static const size_t OFF_WFC = OFF_W1 + SZ_W1;                 // Wfc bf16 [64][640]
static const size_t SZ_WFC  = (size_t)64*640*2;
static const size_t OFF_B0  = OFF_WFC + SZ_WFC;               // f32 [2432]
static const size_t OFF_B1  = OFF_B0 + 2432*4;                // f32 [2432]
static const size_t OFF_BFC = OFF_B1 + 2432*4;                // f32 [64]
static const size_t OFF_DT  = OFF_BFC + 64*4;                 // u32 dtype-probe count
static const size_t WS_NEED = OFF_DT + 4;

// ---------------- helpers ----------------
__device__ __forceinline__ float bf2f(u16 u){ union{u32 i; float f;} v; v.i=(u32)u<<16; return v.f; }
__device__ __forceinline__ u16 f2bf(float f){ union{float f; u32 u;} v; v.f=f; u32 r=v.u+0x7fffu+((v.u>>16)&1u); return (u16)(r>>16); }
__device__ __forceinline__ float sigf(float x){ return __builtin_amdgcn_rcpf(1.f+__builtin_amdgcn_exp2f(-1.4426950408889634f*x)); }
__device__ __forceinline__ float tanhf_(float x){ return 2.f*__builtin_amdgcn_rcpf(1.f+__builtin_amdgcn_exp2f(-2.8853900817779268f*x))-1.f; }
// dtype-adaptive input loads (isf32 is wave-uniform)
__device__ __forceinline__ float ldf(const void* p, size_t i, bool f32){
  return f32 ? ((const float*)p)[i] : bf2f(((const u16*)p)[i]);
}
__device__ __forceinline__ u16 ldh(const void* p, size_t i, bool f32){
  return f32 ? f2bf(((const float*)p)[i]) : ((const u16*)p)[i];
}

// ---------------- dtype probe ----------------
__global__ __launch_bounds__(256,1) void k_detect(const u16* __restrict__ probe, u32* __restrict__ cnt)
{
  int c = 0;
  for (int i = threadIdx.x; i < 65536; i += 256) {
    u16 v = probe[i];
    if (((v >> 7) & 0xFF) == 0xFF) ++c;
  }
  if (c) atomicAdd(cnt, (u32)c);
}

// ---------------- weight/bias repack ----------------
__global__ __launch_bounds__(256,4) void k_prep(
    const void* __restrict__ b0_Wih, const void* __restrict__ b0_bih, const void* __restrict__ b0_bhh,
    const void* __restrict__ b1_Wih, const void* __restrict__ b1_bih, const void* __restrict__ b1_bhh,
    const void* __restrict__ fcW,    const void* __restrict__ fcb,
    u16* __restrict__ W0p, u16* __restrict__ W1p, u16* __restrict__ Wfc,
    float* __restrict__ bias0, float* __restrict__ bias1, float* __restrict__ biasfc,
    const u32* __restrict__ dtf)
{
  const bool isf32 = (*dtf >= 8u);
  const int T0 = 2432*160, T1 = 2432*640, T2 = 64*640;
  const int total = T0 + T1 + T2 + 2432 + 2432 + 64;
  for (int i = blockIdx.x*256 + threadIdx.x; i < total; i += gridDim.x*256) {
    int x = i;
    if (x < T0) {
      int n = x/160, k = x%160;
      int dir = n/1216, cc = n%1216, g = cc/GP, uu = cc%GP;
      W0p[x] = (uu<300 && k<150) ? ldh(b0_Wih, ((size_t)dir*1200 + g*300 + uu)*150 + k, isf32) : (u16)0;
      continue;
    }
    x -= T0;
    if (x < T1) {
      int n = x/640, k = x%640;
      int dir = n/1216, cc = n%1216, g = cc/GP, uu = cc%GP;
      int part = (k>=320), ui = k - part*320;
      W1p[x] = (uu<300 && ui<300) ? ldh(b1_Wih, ((size_t)dir*1200 + g*300 + uu)*600 + part*300 + ui, isf32) : (u16)0;
      continue;
    }
    x -= T1;
    if (x < T2) {
      int n = x/640, k = x%640;
      int part = (k>=320), ui = k - part*320;
      Wfc[x] = (n<50 && ui<300) ? ldh(fcW, (size_t)n*600 + part*300 + ui, isf32) : (u16)0;
      continue;
    }
    x -= T2;
    if (x < 2432) {
      int dir = x/1216, cc = x%1216, g = cc/GP, uu = cc%GP;
      bias0[x] = (uu<300) ? ldf(b0_bih, dir*1200+g*300+uu, isf32) + ldf(b0_bhh, dir*1200+g*300+uu, isf32) : 0.f;
      continue;
    }
    x -= 2432;
    if (x < 2432) {
      int dir = x/1216, cc = x%1216, g = cc/GP, uu = cc%GP;
      bias1[x] = (uu<300) ? ldf(b1_bih, dir*1200+g*300+uu, isf32) + ldf(b1_bhh, dir*1200+g*300+uu, isf32) : 0.f;
      continue;
    }
    x -= 2432;
    biasfc[x] = (x<50) ? ldf(fcb, x, isf32) : 0.f;
  }
}

// ---------------- char LSTM (2 layers, L=16), 64 seqs/WG ----------------
__global__ __launch_bounds__(256,1) void k_char(
    const int* __restrict__ char_ids, const void* __restrict__ cemb,
    const void* __restrict__ cWih, const void* __restrict__ cWhh,
    const void* __restrict__ cbih, const void* __restrict__ cbhh,
    u16* __restrict__ charfeat, const u32* __restrict__ dtf)
{
  __shared__ u16 emb[128][64];   // char embed table, cols 50-63 zero
  __shared__ int ids[16][64];    // [t][seq]
  __shared__ u16 h0s[64][64];
  __shared__ u16 h1s[64][64];
  const bool isf32 = (*dtf >= 8u);
  const int tid = threadIdx.x;
  const int g0  = blockIdx.x * 64;

  for (int e = tid; e < 128*64; e += 256) {
    int row = e>>6, col = e&63;
    (&emb[0][0])[e] = (col<50) ? ldh(cemb, row*50 + col, isf32) : (u16)0;
  }
  for (int e = tid; e < 1024; e += 256) ids[e&15][e>>4] = char_ids[(size_t)g0*16 + e];
  for (int e = tid; e < 4096; e += 256) { (&h0s[0][0])[e] = 0; (&h1s[0][0])[e] = 0; }
  __syncthreads();

  const int w = tid>>6, lane = tid&63, quad = lane>>4, lcol = lane&15;
  const int u = w*16 + lcol;                       // owned unit col

  bf16x8 Wf[2][4][4];
  #pragma unroll
  for (int l=0; l<2; ++l)
    #pragma unroll
    for (int g=0; g<4; ++g)
      #pragma unroll
      for (int kt=0; kt<4; ++kt) {
        union { bf16x8 v; u16 h[8]; } t8;
        #pragma unroll
        for (int q=0; q<8; ++q) {
          int k = kt*32 + quad*8 + q;
          u16 val = 0;
          if (u < 50) {
            if (k < 50)                  val = ldh(cWih, l*10000 + (g*50+u)*50 + k, isf32);
            else if (k >= 64 && k < 114) val = ldh(cWhh, l*10000 + (g*50+u)*50 + (k-64), isf32);
          }
          t8.h[q] = val;
        }
        Wf[l][g][kt] = t8.v;
      }
  float bs[2][4];
  #pragma unroll
  for (int l=0; l<2; ++l)
    #pragma unroll
    for (int g=0; g<4; ++g)
      bs[l][g] = (u<50) ? ldf(cbih, l*200+g*50+u, isf32) + ldf(cbhh, l*200+g*50+u, isf32) : 0.f;

  float c0[4][4] = {}; float c1[4][4] = {};
  float h0n[4][4], h1n[4][4];

  for (int t=0; t<16; ++t) {
    // layer 0
    #pragma unroll
    for (int m=0; m<4; ++m) {
      f32x4 acc[4];
      #pragma unroll
      for (int g=0; g<4; ++g) acc[g] = (f32x4){bs[0][g], bs[0][g], bs[0][g], bs[0][g]};
      #pragma unroll
      for (int kt=0; kt<4; ++kt) {
        bf16x8 a;
        if (kt < 2) { int id = ids[t][m*16+lcol]; a = *(const bf16x8*)&emb[id][kt*32 + quad*8]; }
        else        { a = *(const bf16x8*)&h0s[m*16+lcol][(kt-2)*32 + quad*8]; }
        #pragma unroll
        for (int g=0; g<4; ++g) acc[g] = MFMA16(a, Wf[0][g][kt], acc[g]);
      }
      #pragma unroll
      for (int r=0; r<4; ++r) {
        float cn = sigf(acc[1][r])*c0[m][r] + sigf(acc[0][r])*tanhf_(acc[2][r]);
        c0[m][r] = cn;
        h0n[m][r] = sigf(acc[3][r]) * tanhf_(cn);
      }
    }
    __syncthreads();
    #pragma unroll
    for (int m=0; m<4; ++m)
      #pragma unroll
      for (int r=0; r<4; ++r) h0s[m*16 + quad*4 + r][u] = f2bf(h0n[m][r]);
    __syncthreads();
    // layer 1 (x = h0_t)
    #pragma unroll
    for (int m=0; m<4; ++m) {
      f32x4 acc[4];
      #pragma unroll
      for (int g=0; g<4; ++g) acc[g] = (f32x4){bs[1][g], bs[1][g], bs[1][g], bs[1][g]};
      #pragma unroll
      for (int kt=0; kt<4; ++kt) {
        bf16x8 a = (kt<2) ? *(const bf16x8*)&h0s[m*16+lcol][kt*32 + quad*8]
                          : *(const bf16x8*)&h1s[m*16+lcol][(kt-2)*32 + quad*8];
        #pragma unroll
        for (int g=0; g<4; ++g) acc[g] = MFMA16(a, Wf[1][g][kt], acc[g]);
      }
      #pragma unroll
      for (int r=0; r<4; ++r) {
        float cn = sigf(acc[1][r])*c1[m][r] + sigf(acc[0][r])*tanhf_(acc[2][r]);
        c1[m][r] = cn;
        h1n[m][r] = sigf(acc[3][r]) * tanhf_(cn);
      }
    }
    __syncthreads();
    #pragma unroll
    for (int m=0; m<4; ++m)
      #pragma unroll
      for (int r=0; r<4; ++r) h1s[m*16 + quad*4 + r][u] = f2bf(h1n[m][r]);
    __syncthreads();
  }
  for (int e = tid; e < 4096; e += 256)
    charfeat[(size_t)(g0 + (e>>6))*64 + (e&63)] = (&h1s[0][0])[e];
}

// xg epilogue addressing: n -> (dir, gate, slice j, unit uc); row -> (t, b)
__device__ __forceinline__ size_t xg_addr(int n, int row){
  int dir = n/1216, cc = n%1216, g = cc/GP, cg = cc%GP, jj = cg>>4, uc = cg&15;
  int t = row>>6, b = row&63;
  return (((size_t)dir*256 + t)*NWG + jj)*XGB + (g*16 + uc)*64 + b;
}

// ---------------- L0 input projection: xg = [emb|char] @ W0p^T + bias ----------------
__global__ __launch_bounds__(256,2) void k_proj0(
    const int* __restrict__ word_ids, const void* __restrict__ wemb,
    const u16* __restrict__ charfeat, const u16* __restrict__ W0p,
    const float* __restrict__ bias0, u16* __restrict__ xg, const u32* __restrict__ dtf)
{
  __shared__ u16 As[64][160];
  __shared__ u16 Bst[64][160];
  const bool isf32 = (*dtf >= 8u);
  const int tid = threadIdx.x;
  const int r0 = blockIdx.x*64, n0 = blockIdx.y*64;
  u32* Asu = (u32*)&As[0][0];
  u32* Bsu = (u32*)&Bst[0][0];
  for (int e = tid; e < 64*80; e += 256) {
    int rr = e/80, cu = e%80;
    int r = r0 + rr, t = r>>6, b = r&63;
    u32 v;
    if (cu < 50) {
      int wid = word_ids[b*256 + t];
      if (isf32) {
        const float* wf = (const float*)wemb;
        v = (u32)f2bf(wf[(size_t)wid*100 + cu*2]) | ((u32)f2bf(wf[(size_t)wid*100 + cu*2 + 1]) << 16);
      } else {
        v = ((const u32*)wemb)[(size_t)wid*50 + cu];
      }
    }
    else if (cu < 75) { v = ((const u32*)charfeat)[(size_t)r*32 + (cu-50)]; }
    else              v = 0;
    Asu[rr*80 + cu] = v;
  }
  for (int e = tid; e < 64*80; e += 256) {
    int n = e/80, cu = e%80;
    Bsu[n*80 + cu] = ((const u32*)W0p)[(size_t)(n0+n)*80 + cu];
  }
  __syncthreads();
  const int w = tid>>6, lane = tid&63, quad = lane>>4, lcol = lane&15;
  f32x4 acc[4] = {};
  #pragma unroll
  for (int kt=0; kt<5; ++kt) {
    bf16x8 a = *(const bf16x8*)&As[w*16+lcol][kt*32 + quad*8];
    #pragma unroll
    for (int nt=0; nt<4; ++nt) {
      bf16x8 bb = *(const bf16x8*)&Bst[nt*16+lcol][kt*32 + quad*8];
      acc[nt] = MFMA16(a, bb, acc[nt]);
    }
  }
  #pragma unroll
  for (int nt=0; nt<4; ++nt) {
    int n = n0 + nt*16 + lcol;
    float bia = bias0[n];
    #pragma unroll
    for (int r=0; r<4; ++r) {
      int row = r0 + w*16 + quad*4 + r;
      xg[xg_addr(n, row)] = f2bf(acc[nt][r] + bia);
    }
  }
}

// ---------------- L1 input projection: xg = [h0_fwd|h0_rev] @ W1p^T + bias ----------------
__global__ __launch_bounds__(256,2) void k_proj1(
    const u16* __restrict__ Hbuf, const u16* __restrict__ W1p,
    const float* __restrict__ bias1, u16* __restrict__ xg)
{
  __shared__ u16 As[64][128];
  __shared__ u16 Bst[64][128];
  const int tid = threadIdx.x;
  const int r0 = blockIdx.x*64, n0 = blockIdx.y*64;
  const u32* Hu = (const u32*)Hbuf;
  const u32* Wu = (const u32*)W1p;
  u32* Asu = (u32*)&As[0][0];
  u32* Bsu = (u32*)&Bst[0][0];
  const int w = tid>>6, lane = tid&63, quad = lane>>4, lcol = lane&15;
  f32x4 acc[4] = {};
  for (int ch=0; ch<5; ++ch) {
    __syncthreads();
    for (int e = tid; e < 4096; e += 256) {
      int rr = e>>6, cu = e&63;
      int r = r0 + rr, t = r>>6, b = r&63;
      int kk = ch*128 + cu*2;
      int part = (kk>=320), off = kk - part*320;
      Asu[e] = Hu[(((size_t)part*SLOTS + (part ? 256-t : t+1))*64 + b)*160 + (off>>1)];
    }
    for (int e = tid; e < 4096; e += 256) {
      int n = e>>6, cu = e&63;
      Bsu[e] = Wu[(size_t)(n0+n)*320 + ch*64 + cu];
    }
    __syncthreads();
    #pragma unroll
    for (int kt=0; kt<4; ++kt) {
      bf16x8 a = *(const bf16x8*)&As[w*16+lcol][kt*32 + quad*8];
      #pragma unroll
      for (int nt=0; nt<4; ++nt) {
        bf16x8 bb = *(const bf16x8*)&Bst[nt*16+lcol][kt*32 + quad*8];
        acc[nt] = MFMA16(a, bb, acc[nt]);
      }
    }
  }
  #pragma unroll
  for (int nt=0; nt<4; ++nt) {
    int n = n0 + nt*16 + lcol;
    float bia = bias1[n];
    #pragma unroll
    for (int r=0; r<4; ++r) {
      int row = r0 + w*16 + quad*4 + r;
      xg[xg_addr(n, row)] = f2bf(acc[nt][r] + bia);
    }
  }
}

// ---------------- recurrent scan: sentinel-in-data sync (no flags, no drains) ----------------
// H slots (t>=1) are pre-filled with 0xFFFF. Producers store final h words (u32, agent
// scope) exactly once; a data word can never be 0xFFFFFFFF (|h|<1 -> finite bf16). A
// consumer simply re-loads its h fragment until no word is sentinel: any non-sentinel
// read is valid regardless of store visibility order. Slice NWG-1 also zeroes the pad
// units 304..319 each step (polled by quads 2-3 at kt=9, and read by proj1/fc).
__global__ __launch_bounds__(256,1) void k_scan(
    const u16* __restrict__ xg, const void* __restrict__ Whh,
    u16* __restrict__ Hbuf, const u32* __restrict__ dtf)
{
  const bool isf32 = (*dtf >= 8u);
  const int bx = blockIdx.x;
  const int d = bx / NWG, j = bx % NWG;
  const int tid = threadIdx.x;
  const int w = tid>>6, lane = tid&63, quad = lane>>4, lcol = lane&15;
  const int u = j*16 + lcol;                      // owned unit col (n)
  const int brow = w*16;                          // M-tile batch base

  bf16x8 Bf[4][10];
  #pragma unroll
  for (int g=0; g<4; ++g)
    #pragma unroll
    for (int kt=0; kt<10; ++kt) {
      union { bf16x8 v; u16 h[8]; } t8;
      #pragma unroll
      for (int q=0; q<8; ++q) {
        int k = kt*32 + quad*8 + q;
        t8.h[q] = (u < 300 && k < 300) ? ldh(Whh, ((size_t)d*1200 + g*300 + u)*300 + k, isf32) : (u16)0;
      }
      Bf[g][kt] = t8.v;
    }

  float c[4] = {0.f,0.f,0.f,0.f};

  for (int t=0; t<256; ++t) {
    const int tt = d ? (255 - t) : t;
    // prefetch xg for this step (independent of h) — in flight during the poll
    const volatile u64* xp = (const volatile u64*)(xg + (((size_t)d*256 + tt)*NWG + j)*XGB);
    u64 xq[4];
    #pragma unroll
    for (int g=0; g<4; ++g)
      xq[g] = xp[((g*16 + lcol)*64 + brow + quad*4) >> 2];

    // poll h[t] directly: reload fragment until sentinel-free
    union HU { bf16x8 v; u64 q[2]; u32 w4[4]; };
    HU a[10];
    const u16* hp = Hbuf + (((size_t)d*SLOTS + t)*64 + (brow + lcol))*HP + quad*8;
    while (true) {
      #pragma unroll
      for (int kt=0; kt<10; ++kt) {
        a[kt].q[0] = __hip_atomic_load((const u64*)(hp + kt*32),     __ATOMIC_RELAXED, __HIP_MEMORY_SCOPE_AGENT);
        a[kt].q[1] = __hip_atomic_load((const u64*)(hp + kt*32 + 4), __ATOMIC_RELAXED, __HIP_MEMORY_SCOPE_AGENT);
      }
      u32 mx = 0u;
      #pragma unroll
      for (int kt=0; kt<10; ++kt)
        #pragma unroll
        for (int i=0; i<4; ++i) { u32 ww = a[kt].w4[i]; mx = (ww > mx) ? ww : mx; }
      if (__ballot(mx != 0xFFFFFFFFu) == ~0ull) break;
      __builtin_amdgcn_s_sleep(1);
    }

    f32x4 acc[4];
    #pragma unroll
    for (int g=0; g<4; ++g) {
      union { u64 q; u16 h[4]; } t4; t4.q = xq[g];
      #pragma unroll
      for (int r=0; r<4; ++r) acc[g][r] = bf2f(t4.h[r]);
    }
    #pragma unroll
    for (int kt=0; kt<10; ++kt) {
      #pragma unroll
      for (int g=0; g<4; ++g) acc[g] = MFMA16(a[kt].v, Bf[g][kt], acc[g]);
    }
    #pragma unroll
    for (int r=0; r<4; ++r) {
      float cn = sigf(acc[1][r])*c[r] + sigf(acc[0][r])*tanhf_(acc[2][r]);
      c[r] = cn;
      float h = sigf(acc[3][r]) * tanhf_(cn);
      u32 mine = (u32)f2bf(h);
      u32 other = (u32)__shfl_xor((int)mine, 1, 64);
      if ((lcol & 1) == 0) {
        u32 word = mine | (other << 16);
        int b = brow + quad*4 + r;
        size_t e = (((size_t)d*SLOTS + (t+1))*64 + b)*HP + j*16 + lcol;
        __hip_atomic_store((u32*)(Hbuf + e), word, __ATOMIC_RELAXED, __HIP_MEMORY_SCOPE_AGENT);
      }
    }
    if (j == NWG-1) {
      // zero pad units 304..319 of slot t+1 so consumers' sentinel poll completes
      #pragma unroll
      for (int r=0; r<4; ++r) {
        if ((lcol & 1) == 0) {
          int b = brow + quad*4 + r;
          size_t e2 = (((size_t)d*SLOTS + (t+1))*64 + b)*HP + 304 + lcol;
          __hip_atomic_store((u32*)(Hbuf + e2), 0u, __ATOMIC_RELAXED, __HIP_MEMORY_SCOPE_AGENT);
        }
      }
    }
    // no drain, no flag: the data itself signals readiness
  }
}

// ---------------- FC + log_softmax ----------------
__global__ __launch_bounds__(256,2) void k_fc(
    const u16* __restrict__ Hbuf, const u16* __restrict__ Wfc,
    const float* __restrict__ biasfc, void* __restrict__ outv, const u32* __restrict__ dtf)
{
  __shared__ u16 As[64][128];
  __shared__ u16 Bst[64][128];
  const bool isf32 = (*dtf >= 8u);
  const int tid = threadIdx.x;
  const int r0 = blockIdx.x*64;
  const u32* Hu = (const u32*)Hbuf;
  const u32* Wu = (const u32*)Wfc;
  u32* Asu = (u32*)&As[0][0];
  u32* Bsu = (u32*)&Bst[0][0];
  const int w = tid>>6, lane = tid&63, quad = lane>>4, lcol = lane&15;
  f32x4 acc[4] = {};
  for (int ch=0; ch<5; ++ch) {
    __syncthreads();
    for (int e = tid; e < 4096; e += 256) {
      int rr = e>>6, cu = e&63;
      int r = r0 + rr, t = r>>6, b = r&63;
      int kk = ch*128 + cu*2;
      int part = (kk>=320), off = kk - part*320;
      Asu[e] = Hu[(((size_t)part*SLOTS + (part ? 256-t : t+1))*64 + b)*160 + (off>>1)];
    }
    for (int e = tid; e < 4096; e += 256) {
      int n = e>>6, cu = e&63;
      Bsu[e] = Wu[(size_t)n*320 + ch*64 + cu];
    }
    __syncthreads();
    #pragma unroll
    for (int kt=0; kt<4; ++kt) {
      bf16x8 a = *(const bf16x8*)&As[w*16+lcol][kt*32 + quad*8];
      #pragma unroll
      for (int nt=0; nt<4; ++nt) {
        bf16x8 bb = *(const bf16x8*)&Bst[nt*16+lcol][kt*32 + quad*8];
        acc[nt] = MFMA16(a, bb, acc[nt]);
      }
    }
  }
  float vals[4][4];
  #pragma unroll
  for (int nt=0; nt<4; ++nt) {
    int cc = nt*16 + lcol;
    float bia = biasfc[cc];
    #pragma unroll
    for (int r=0; r<4; ++r) vals[nt][r] = (cc < 50) ? (acc[nt][r] + bia) : -3.0e38f;
  }
  float lz[4];
  #pragma unroll
  for (int r=0; r<4; ++r) {
    float m = fmaxf(fmaxf(vals[0][r], vals[1][r]), fmaxf(vals[2][r], vals[3][r]));
    #pragma unroll
    for (int dd=1; dd<16; dd<<=1) m = fmaxf(m, __shfl_xor(m, dd, 64));
    float s = 0.f;
    #pragma unroll
    for (int nt=0; nt<4; ++nt) s += __builtin_amdgcn_exp2f((vals[nt][r]-m)*1.4426950408889634f);
    #pragma unroll
    for (int dd=1; dd<16; dd<<=1) s += __shfl_xor(s, dd, 64);
    lz[r] = m + __builtin_amdgcn_logf(s)*0.6931471805599453f;
  }
  #pragma unroll
  for (int nt=0; nt<4; ++nt) {
    int cc = nt*16 + lcol;
    if (cc < 50) {
      #pragma unroll
      for (int r=0; r<4; ++r) {
        int row = r0 + w*16 + quad*4 + r;
        int t = row>>6, b = row&63;
        size_t idx = ((size_t)b*256 + t)*50 + cc;
        float v = vals[nt][r] - lz[r];
        if (isf32) ((float*)outv)[idx] = v;
        else       ((u16*)outv)[idx] = f2bf(v);
      }
    }
  }
}

// ---------------- launch ----------------
extern "C" void kernel_launch(void* const* d_in, const int* in_sizes, int n_in,
                              void* d_out, int out_size, void* d_ws, size_t ws_size,
                              hipStream_t stream) {
  (void)in_sizes; (void)n_in; (void)out_size;
  if (ws_size < WS_NEED) return;

  const int* word_ids = (const int*)d_in[0];
  const int* char_ids = (const int*)d_in[1];
  const void* wemb   = d_in[2];
  const void* cemb   = d_in[3];
  const void* cWih   = d_in[4];
  const void* cWhh   = d_in[5];
  const void* cbih   = d_in[6];
  const void* cbhh   = d_in[7];
  const void* b0_Wih = d_in[8];
  const void* b0_Whh = d_in[9];
  const void* b0_bih = d_in[10];
  const void* b0_bhh = d_in[11];
  const void* b1_Wih = d_in[12];
  const void* b1_Whh = d_in[13];
  const void* b1_bih = d_in[14];
  const void* b1_bhh = d_in[15];
  const void* fcW    = d_in[16];
  const void* fcb    = d_in[17];

  char* ws = (char*)d_ws;
  u16*   xg   = (u16*)(ws + OFF_XG);
  u16*   H0   = (u16*)(ws + OFF_H0);
  u16*   H1   = (u16*)(ws + OFF_H1);
  u16*   cf   = (u16*)(ws + OFF_CF);
  u16*   W0p  = (u16*)(ws + OFF_W0);
  u16*   W1p  = (u16*)(ws + OFF_W1);
  u16*   Wfc  = (u16*)(ws + OFF_WFC);
  float* bia0 = (float*)(ws + OFF_B0);
  float* bia1 = (float*)(ws + OFF_B1);
  float* biaf = (float*)(ws + OFF_BFC);
  u32*   dtf  = (u32*)(ws + OFF_DT);

  // sentinel-fill H buffers, then zero the initial h slots (slot 0, both dirs, both layers)
  hipMemsetAsync(H0, 0xFF, SZ_HB, stream);
  hipMemsetAsync(H1, 0xFF, SZ_HB, stream);
  hipMemsetAsync(H0,                       0, (size_t)64*HP*2, stream);
  hipMemsetAsync(H0 + (size_t)SLOTS*64*HP, 0, (size_t)64*HP*2, stream);
  hipMemsetAsync(H1,                       0, (size_t)64*HP*2, stream);
  hipMemsetAsync(H1 + (size_t)SLOTS*64*HP, 0, (size_t)64*HP*2, stream);
  hipMemsetAsync(dtf, 0, 4, stream);

  k_detect<<<1, 256, 0, stream>>>((const u16*)wemb, dtf);
  k_prep<<<7780, 256, 0, stream>>>(b0_Wih, b0_bih, b0_bhh, b1_Wih, b1_bih, b1_bhh,
                                   fcW, fcb, W0p, W1p, Wfc, bia0, bia1, biaf, dtf);
  k_char<<<256, 256, 0, stream>>>(char_ids, cemb, cWih, cWhh, cbih, cbhh, cf, dtf);
  k_proj0<<<dim3(256,38), 256, 0, stream>>>(word_ids, wemb, cf, W0p, bia0, xg, dtf);
  k_scan<<<2*NWG, 256, 0, stream>>>(xg, b0_Whh, H0, dtf);
  k_proj1<<<dim3(256,38), 256, 0, stream>>>(H0, W1p, bia1, xg);
  k_scan<<<2*NWG, 256, 0, stream>>>(xg, b1_Whh, H1, dtf);
  k_fc<<<256, 256, 0, stream>>>(H1, Wfc, biaf, d_out, dtf);
}

// Round 8
// 2611.804 us; speedup vs baseline: 1.1673x; 1.1142x over previous
//
#include <hip/hip_runtime.h>

typedef unsigned short u16;
typedef unsigned int   u32;
typedef unsigned long long u64;
typedef __attribute__((ext_vector_type(8))) short bf16x8;
typedef __attribute__((ext_vector_type(4))) float f32x4;

#define MFMA16(a,b,c) __builtin_amdgcn_mfma_f32_16x16x32_bf16((a),(b),(c),0,0,0)

// model dims: B=64 S=256 L=16 CE=50 E=100 H=300 NCLS=50
#define NWG   19      // ceil(300/16) h-slice WGs per direction
#define HP    320     // padded hidden (K for recurrent MFMA)
#define GP    304     // per-gate padded width (19*16)
#define XGB   4096    // u16 per (t,j) xg block, C-fragment order: [g][w][lane][r]
#define SLOTS 257     // h time slots (slot 0 = initial zero state)
#define HSLOT 20480   // u16 per h slot, A-fragment order: [kt 10][b 64][ku 32]

// ---------------- workspace layout (bytes) ----------------
static const size_t OFF_XG  = 0;                              // bf16 [2][256][19][4096]
static const size_t SZ_XG   = (size_t)2*256*NWG*XGB*2;
static const size_t OFF_H0  = OFF_XG + SZ_XG;                 // bf16 [2][257][20480]
static const size_t SZ_HB   = (size_t)2*SLOTS*HSLOT*2;
static const size_t OFF_H1  = OFF_H0 + SZ_HB;
static const size_t OFF_CF  = OFF_H1 + SZ_HB;                 // charfeat bf16 [16384][64]
static const size_t SZ_CF   = (size_t)16384*64*2;
static const size_t OFF_W0  = OFF_CF + SZ_CF;                 // W0p bf16 [2432][160]
static const size_t SZ_W0   = (size_t)2432*160*2;
static const size_t OFF_W1  = OFF_W0 + SZ_W0;                 // W1p bf16 [2432][640]
static const size_t SZ_W1   = (size_t)2432*640*2;
static const size_t OFF_WFC = OFF_W1 + SZ_W1;                 // Wfc bf16 [64][640]
static const size_t SZ_WFC  = (size_t)64*640*2;
static const size_t OFF_B0  = OFF_WFC + SZ_WFC;               // f32 [2432]
static const size_t OFF_B1  = OFF_B0 + 2432*4;                // f32 [2432]
static const size_t OFF_BFC = OFF_B1 + 2432*4;                // f32 [64]
static const size_t OFF_DT  = OFF_BFC + 64*4;                 // u32 dtype-probe count
static const size_t WS_NEED = OFF_DT + 4;

// ---------------- helpers ----------------
__device__ __forceinline__ float bf2f(u16 u){ union{u32 i; float f;} v; v.i=(u32)u<<16; return v.f; }
__device__ __forceinline__ u16 f2bf(float f){ union{float f; u32 u;} v; v.f=f; u32 r=v.u+0x7fffu+((v.u>>16)&1u); return (u16)(r>>16); }
__device__ __forceinline__ float sigf(float x){ return __builtin_amdgcn_rcpf(1.f+__builtin_amdgcn_exp2f(-1.4426950408889634f*x)); }
__device__ __forceinline__ float tanhf_(float x){ return 2.f*__builtin_amdgcn_rcpf(1.f+__builtin_amdgcn_exp2f(-2.8853900817779268f*x))-1.f; }
// dtype-adaptive input loads (isf32 is wave-uniform)
__device__ __forceinline__ float ldf(const void* p, size_t i, bool f32){
  return f32 ? ((const float*)p)[i] : bf2f(((const u16*)p)[i]);
}
__device__ __forceinline__ u16 ldh(const void* p, size_t i, bool f32){
  return f32 ? f2bf(((const float*)p)[i]) : ((const u16*)p)[i];
}

// ---------------- dtype probe ----------------
__global__ __launch_bounds__(256,1) void k_detect(const u16* __restrict__ probe, u32* __restrict__ cnt)
{
  int c = 0;
  for (int i = threadIdx.x; i < 65536; i += 256) {
    u16 v = probe[i];
    if (((v >> 7) & 0xFF) == 0xFF) ++c;
  }
  if (c) atomicAdd(cnt, (u32)c);
}

// ---------------- weight/bias repack ----------------
__global__ __launch_bounds__(256,4) void k_prep(
    const void* __restrict__ b0_Wih, const void* __restrict__ b0_bih, const void* __restrict__ b0_bhh,
    const void* __restrict__ b1_Wih, const void* __restrict__ b1_bih, const void* __restrict__ b1_bhh,
    const void* __restrict__ fcW,    const void* __restrict__ fcb,
    u16* __restrict__ W0p, u16* __restrict__ W1p, u16* __restrict__ Wfc,
    float* __restrict__ bias0, float* __restrict__ bias1, float* __restrict__ biasfc,
    const u32* __restrict__ dtf)
{
  const bool isf32 = (*dtf >= 8u);
  const int T0 = 2432*160, T1 = 2432*640, T2 = 64*640;
  const int total = T0 + T1 + T2 + 2432 + 2432 + 64;
  for (int i = blockIdx.x*256 + threadIdx.x; i < total; i += gridDim.x*256) {
    int x = i;
    if (x < T0) {
      int n = x/160, k = x%160;
      int dir = n/1216, cc = n%1216, g = cc/GP, uu = cc%GP;
      W0p[x] = (uu<300 && k<150) ? ldh(b0_Wih, ((size_t)dir*1200 + g*300 + uu)*150 + k, isf32) : (u16)0;
      continue;
    }
    x -= T0;
    if (x < T1) {
      int n = x/640, k = x%640;
      int dir = n/1216, cc = n%1216, g = cc/GP, uu = cc%GP;
      int part = (k>=320), ui = k - part*320;
      W1p[x] = (uu<300 && ui<300) ? ldh(b1_Wih, ((size_t)dir*1200 + g*300 + uu)*600 + part*300 + ui, isf32) : (u16)0;
      continue;
    }
    x -= T1;
    if (x < T2) {
      int n = x/640, k = x%640;
      int part = (k>=320), ui = k - part*320;
      Wfc[x] = (n<50 && ui<300) ? ldh(fcW, (size_t)n*600 + part*300 + ui, isf32) : (u16)0;
      continue;
    }
    x -= T2;
    if (x < 2432) {
      int dir = x/1216, cc = x%1216, g = cc/GP, uu = cc%GP;
      bias0[x] = (uu<300) ? ldf(b0_bih, dir*1200+g*300+uu, isf32) + ldf(b0_bhh, dir*1200+g*300+uu, isf32) : 0.f;
      continue;
    }
    x -= 2432;
    if (x < 2432) {
      int dir = x/1216, cc = x%1216, g = cc/GP, uu = cc%GP;
      bias1[x] = (uu<300) ? ldf(b1_bih, dir*1200+g*300+uu, isf32) + ldf(b1_bhh, dir*1200+g*300+uu, isf32) : 0.f;
      continue;
    }
    x -= 2432;
    biasfc[x] = (x<50) ? ldf(fcb, x, isf32) : 0.f;
  }
}

// ---------------- char LSTM (2 layers, L=16), 64 seqs/WG ----------------
// h arrays padded 64->72 cols: write pattern was 8-way bank-conflicted at stride 64
// (8.2M SQ_LDS_BANK_CONFLICT observed); stride 72 u16 rotates banks by 4 per row.
__global__ __launch_bounds__(256,1) void k_char(
    const int* __restrict__ char_ids, const void* __restrict__ cemb,
    const void* __restrict__ cWih, const void* __restrict__ cWhh,
    const void* __restrict__ cbih, const void* __restrict__ cbhh,
    u16* __restrict__ charfeat, const u32* __restrict__ dtf)
{
  __shared__ u16 emb[128][64];   // char embed table, cols 50-63 zero
  __shared__ int ids[16][64];    // [t][seq]
  __shared__ u16 h0s[64][72];
  __shared__ u16 h1s[64][72];
  const bool isf32 = (*dtf >= 8u);
  const int tid = threadIdx.x;
  const int g0  = blockIdx.x * 64;

  for (int e = tid; e < 128*64; e += 256) {
    int row = e>>6, col = e&63;
    (&emb[0][0])[e] = (col<50) ? ldh(cemb, row*50 + col, isf32) : (u16)0;
  }
  for (int e = tid; e < 1024; e += 256) ids[e&15][e>>4] = char_ids[(size_t)g0*16 + e];
  for (int e = tid; e < 4096; e += 256) { h0s[e>>6][e&63] = 0; h1s[e>>6][e&63] = 0; }
  __syncthreads();

  const int w = tid>>6, lane = tid&63, quad = lane>>4, lcol = lane&15;
  const int u = w*16 + lcol;                       // owned unit col

  bf16x8 Wf[2][4][4];
  #pragma unroll
  for (int l=0; l<2; ++l)
    #pragma unroll
    for (int g=0; g<4; ++g)
      #pragma unroll
      for (int kt=0; kt<4; ++kt) {
        union { bf16x8 v; u16 h[8]; } t8;
        #pragma unroll
        for (int q=0; q<8; ++q) {
          int k = kt*32 + quad*8 + q;
          u16 val = 0;
          if (u < 50) {
            if (k < 50)                  val = ldh(cWih, l*10000 + (g*50+u)*50 + k, isf32);
            else if (k >= 64 && k < 114) val = ldh(cWhh, l*10000 + (g*50+u)*50 + (k-64), isf32);
          }
          t8.h[q] = val;
        }
        Wf[l][g][kt] = t8.v;
      }
  float bs[2][4];
  #pragma unroll
  for (int l=0; l<2; ++l)
    #pragma unroll
    for (int g=0; g<4; ++g)
      bs[l][g] = (u<50) ? ldf(cbih, l*200+g*50+u, isf32) + ldf(cbhh, l*200+g*50+u, isf32) : 0.f;

  float c0[4][4] = {}; float c1[4][4] = {};
  float h0n[4][4], h1n[4][4];

  for (int t=0; t<16; ++t) {
    // layer 0
    #pragma unroll
    for (int m=0; m<4; ++m) {
      f32x4 acc[4];
      #pragma unroll
      for (int g=0; g<4; ++g) acc[g] = (f32x4){bs[0][g], bs[0][g], bs[0][g], bs[0][g]};
      #pragma unroll
      for (int kt=0; kt<4; ++kt) {
        bf16x8 a;
        if (kt < 2) { int id = ids[t][m*16+lcol]; a = *(const bf16x8*)&emb[id][kt*32 + quad*8]; }
        else        { a = *(const bf16x8*)&h0s[m*16+lcol][(kt-2)*32 + quad*8]; }
        #pragma unroll
        for (int g=0; g<4; ++g) acc[g] = MFMA16(a, Wf[0][g][kt], acc[g]);
      }
      #pragma unroll
      for (int r=0; r<4; ++r) {
        float cn = sigf(acc[1][r])*c0[m][r] + sigf(acc[0][r])*tanhf_(acc[2][r]);
        c0[m][r] = cn;
        h0n[m][r] = sigf(acc[3][r]) * tanhf_(cn);
      }
    }
    __syncthreads();
    #pragma unroll
    for (int m=0; m<4; ++m)
      #pragma unroll
      for (int r=0; r<4; ++r) h0s[m*16 + quad*4 + r][u] = f2bf(h0n[m][r]);
    __syncthreads();
    // layer 1 (x = h0_t)
    #pragma unroll
    for (int m=0; m<4; ++m) {
      f32x4 acc[4];
      #pragma unroll
      for (int g=0; g<4; ++g) acc[g] = (f32x4){bs[1][g], bs[1][g], bs[1][g], bs[1][g]};
      #pragma unroll
      for (int kt=0; kt<4; ++kt) {
        bf16x8 a = (kt<2) ? *(const bf16x8*)&h0s[m*16+lcol][kt*32 + quad*8]
                          : *(const bf16x8*)&h1s[m*16+lcol][(kt-2)*32 + quad*8];
        #pragma unroll
        for (int g=0; g<4; ++g) acc[g] = MFMA16(a, Wf[1][g][kt], acc[g]);
      }
      #pragma unroll
      for (int r=0; r<4; ++r) {
        float cn = sigf(acc[1][r])*c1[m][r] + sigf(acc[0][r])*tanhf_(acc[2][r]);
        c1[m][r] = cn;
        h1n[m][r] = sigf(acc[3][r]) * tanhf_(cn);
      }
    }
    __syncthreads();
    #pragma unroll
    for (int m=0; m<4; ++m)
      #pragma unroll
      for (int r=0; r<4; ++r) h1s[m*16 + quad*4 + r][u] = f2bf(h1n[m][r]);
    __syncthreads();
  }
  for (int e = tid; e < 4096; e += 256)
    charfeat[(size_t)(g0 + (e>>6))*64 + (e&63)] = h1s[e>>6][e&63];
}

// xg epilogue addressing, C-fragment order: block(t,j) + [g][w=b>>4][lane=((b>>2)&3)*16+uc][r=b&3]
__device__ __forceinline__ size_t xg_addr(int n, int row){
  int dir = n/1216, cc = n%1216, g = cc/GP, cg = cc%GP, jj = cg>>4, uc = cg&15;
  int t = row>>6, b = row&63;
  size_t off = ((size_t)(g*4 + (b>>4))*64 + ((b>>2)&3)*16 + uc)*4 + (b&3);
  return (((size_t)dir*256 + t)*NWG + jj)*XGB + off;
}

// ---------------- L0 input projection: xg = [emb|char] @ W0p^T + bias ----------------
__global__ __launch_bounds__(256,2) void k_proj0(
    const int* __restrict__ word_ids, const void* __restrict__ wemb,
    const u16* __restrict__ charfeat, const u16* __restrict__ W0p,
    const float* __restrict__ bias0, u16* __restrict__ xg, const u32* __restrict__ dtf)
{
  __shared__ u16 As[64][160];
  __shared__ u16 Bst[64][160];
  const bool isf32 = (*dtf >= 8u);
  const int tid = threadIdx.x;
  const int r0 = blockIdx.x*64, n0 = blockIdx.y*64;
  u32* Asu = (u32*)&As[0][0];
  u32* Bsu = (u32*)&Bst[0][0];
  for (int e = tid; e < 64*80; e += 256) {
    int rr = e/80, cu = e%80;
    int r = r0 + rr, t = r>>6, b = r&63;
    u32 v;
    if (cu < 50) {
      int wid = word_ids[b*256 + t];
      if (isf32) {
        const float* wf = (const float*)wemb;
        v = (u32)f2bf(wf[(size_t)wid*100 + cu*2]) | ((u32)f2bf(wf[(size_t)wid*100 + cu*2 + 1]) << 16);
      } else {
        v = ((const u32*)wemb)[(size_t)wid*50 + cu];
      }
    }
    else if (cu < 75) { v = ((const u32*)charfeat)[(size_t)r*32 + (cu-50)]; }
    else              v = 0;
    Asu[rr*80 + cu] = v;
  }
  for (int e = tid; e < 64*80; e += 256) {
    int n = e/80, cu = e%80;
    Bsu[n*80 + cu] = ((const u32*)W0p)[(size_t)(n0+n)*80 + cu];
  }
  __syncthreads();
  const int w = tid>>6, lane = tid&63, quad = lane>>4, lcol = lane&15;
  f32x4 acc[4] = {};
  #pragma unroll
  for (int kt=0; kt<5; ++kt) {
    bf16x8 a = *(const bf16x8*)&As[w*16+lcol][kt*32 + quad*8];
    #pragma unroll
    for (int nt=0; nt<4; ++nt) {
      bf16x8 bb = *(const bf16x8*)&Bst[nt*16+lcol][kt*32 + quad*8];
      acc[nt] = MFMA16(a, bb, acc[nt]);
    }
  }
  #pragma unroll
  for (int nt=0; nt<4; ++nt) {
    int n = n0 + nt*16 + lcol;
    float bia = bias0[n];
    #pragma unroll
    for (int r=0; r<4; ++r) {
      int row = r0 + w*16 + quad*4 + r;
      xg[xg_addr(n, row)] = f2bf(acc[nt][r] + bia);
    }
  }
}

// ---------------- L1 input projection: xg = [h0_fwd|h0_rev] @ W1p^T + bias ----------------
// H is in A-fragment order: elem(u,b) = ((u>>5)*64 + b)*32 + (u&31); u>=304 is never
// written (kt9 upper half) -> zero-fill in staging.
__global__ __launch_bounds__(256,2) void k_proj1(
    const u16* __restrict__ Hbuf, const u16* __restrict__ W1p,
    const float* __restrict__ bias1, u16* __restrict__ xg)
{
  __shared__ u16 As[64][128];
  __shared__ u16 Bst[64][128];
  const int tid = threadIdx.x;
  const int r0 = blockIdx.x*64, n0 = blockIdx.y*64;
  const u32* Hu = (const u32*)Hbuf;
  const u32* Wu = (const u32*)W1p;
  u32* Asu = (u32*)&As[0][0];
  u32* Bsu = (u32*)&Bst[0][0];
  const int w = tid>>6, lane = tid&63, quad = lane>>4, lcol = lane&15;
  f32x4 acc[4] = {};
  for (int ch=0; ch<5; ++ch) {
    __syncthreads();
    for (int e = tid; e < 4096; e += 256) {
      int rr = e>>6, cu = e&63;
      int r = r0 + rr, t = r>>6, b = r&63;
      int kk = ch*128 + cu*2;
      int part = (kk>=320), uu = kk - part*320;
      u32 v = 0;
      if (uu < 304) {
        size_t slot = part ? (size_t)(256 - t) : (size_t)(t + 1);
        v = Hu[(size_t)part*SLOTS*10240 + slot*10240 + ((size_t)(uu>>5)*64 + b)*16 + ((uu&31)>>1)];
      }
      Asu[e] = v;
    }
    for (int e = tid; e < 4096; e += 256) {
      int n = e>>6, cu = e&63;
      Bsu[e] = Wu[(size_t)(n0+n)*320 + ch*64 + cu];
    }
    __syncthreads();
    #pragma unroll
    for (int kt=0; kt<4; ++kt) {
      bf16x8 a = *(const bf16x8*)&As[w*16+lcol][kt*32 + quad*8];
      #pragma unroll
      for (int nt=0; nt<4; ++nt) {
        bf16x8 bb = *(const bf16x8*)&Bst[nt*16+lcol][kt*32 + quad*8];
        acc[nt] = MFMA16(a, bb, acc[nt]);
      }
    }
  }
  #pragma unroll
  for (int nt=0; nt<4; ++nt) {
    int n = n0 + nt*16 + lcol;
    float bia = bias1[n];
    #pragma unroll
    for (int r=0; r<4; ++r) {
      int row = r0 + w*16 + quad*4 + r;
      xg[xg_addr(n, row)] = f2bf(acc[nt][r] + bia);
    }
  }
}

// ---------------- recurrent scan: sentinel-in-data, fragment-major H (coalesced) ----------------
// H slot = [kt 10][b 64][ku 32] u16: a wave's A-fragment for k-tile kt is the contiguous
// 1-KB range [(kt*64+brow)*64B, +1KB) -> poll = 10 coalesced bursts (vs 640 scattered
// 16-B requests in the old [b][u] layout). Waves are fully independent: wave w consumes
// exactly the rows produced by the 19 producer waves with the same w. kt9 upper half
// (u 304..319) is never written: zero-filled in registers, never polled.
__global__ __launch_bounds__(256,1) void k_scan(
    const u16* __restrict__ xg, const void* __restrict__ Whh,
    u16* __restrict__ Hbuf, const u32* __restrict__ dtf)
{
  const bool isf32 = (*dtf >= 8u);
  const int bx = blockIdx.x;
  const int d = bx / NWG, j = bx % NWG;
  const int tid = threadIdx.x;
  const int w = tid>>6, lane = tid&63, quad = lane>>4, lcol = lane&15;
  const int u = j*16 + lcol;                      // owned unit col (n)
  const int brow = w*16;                          // M-tile batch base
  const int ktj = j>>1, kub = (j&1)*16;           // this WG's store tile coords

  bf16x8 Bf[4][10];
  #pragma unroll
  for (int g=0; g<4; ++g)
    #pragma unroll
    for (int kt=0; kt<10; ++kt) {
      union { bf16x8 v; u16 h[8]; } t8;
      #pragma unroll
      for (int q=0; q<8; ++q) {
        int k = kt*32 + quad*8 + q;
        t8.h[q] = (u < 300 && k < 300) ? ldh(Whh, ((size_t)d*1200 + g*300 + u)*300 + k, isf32) : (u16)0;
      }
      Bf[g][kt] = t8.v;
    }

  float c[4] = {0.f,0.f,0.f,0.f};
  const bool okq = (quad < 2);                    // kt9 lower half exists (u 288..303)

  for (int t=0; t<256; ++t) {
    const int tt = d ? (255 - t) : t;
    // xg: 4 coalesced 8-B loads (C-fragment order), in flight during the poll
    const u64* xp = (const u64*)(xg + (((size_t)d*256 + tt)*NWG + j)*XGB);
    u64 xq[4];
    #pragma unroll
    for (int g=0; g<4; ++g) xq[g] = xp[(g*4 + w)*64 + lane];

    // poll h[t]: coalesced fragment loads, per-wave independent, sentinel = 0xFFFFFFFF
    union HU { bf16x8 v; u64 q[2]; u32 w4[4]; };
    HU a[10];
    const u64* hp = (const u64*)Hbuf + (((size_t)d*SLOTS + t)*HSLOT >> 2);
    while (true) {
      #pragma unroll
      for (int kt=0; kt<9; ++kt) {
        size_t bi = (size_t)(kt*64 + brow + lcol)*8 + quad*2;
        a[kt].q[0] = __hip_atomic_load(hp + bi,     __ATOMIC_RELAXED, __HIP_MEMORY_SCOPE_AGENT);
        a[kt].q[1] = __hip_atomic_load(hp + bi + 1, __ATOMIC_RELAXED, __HIP_MEMORY_SCOPE_AGENT);
      }
      if (okq) {
        size_t bi = (size_t)(9*64 + brow + lcol)*8 + quad*2;
        a[9].q[0] = __hip_atomic_load(hp + bi,     __ATOMIC_RELAXED, __HIP_MEMORY_SCOPE_AGENT);
        a[9].q[1] = __hip_atomic_load(hp + bi + 1, __ATOMIC_RELAXED, __HIP_MEMORY_SCOPE_AGENT);
      } else { a[9].q[0] = 0; a[9].q[1] = 0; }
      u32 mx = 0u;
      #pragma unroll
      for (int kt=0; kt<10; ++kt)
        #pragma unroll
        for (int i=0; i<4; ++i) { u32 ww = a[kt].w4[i]; mx = (ww > mx) ? ww : mx; }
      if (__ballot(mx != 0xFFFFFFFFu) == ~0ull) break;   // wave-level gate only
      __builtin_amdgcn_s_sleep(1);
    }

    f32x4 acc[4];
    #pragma unroll
    for (int g=0; g<4; ++g) {
      union { u64 q; u16 h[4]; } t4; t4.q = xq[g];
      #pragma unroll
      for (int r=0; r<4; ++r) acc[g][r] = bf2f(t4.h[r]);
    }
    #pragma unroll
    for (int kt=0; kt<10; ++kt) {
      #pragma unroll
      for (int g=0; g<4; ++g) acc[g] = MFMA16(a[kt].v, Bf[g][kt], acc[g]);
    }
    size_t sbase = ((size_t)d*SLOTS + (t+1))*HSLOT;
    #pragma unroll
    for (int r=0; r<4; ++r) {
      float cn = sigf(acc[1][r])*c[r] + sigf(acc[0][r])*tanhf_(acc[2][r]);
      c[r] = cn;
      float h = sigf(acc[3][r]) * tanhf_(cn);
      u32 mine = (u32)f2bf(h);
      u32 other = (u32)__shfl_xor((int)mine, 1, 64);
      if ((lcol & 1) == 0) {
        u32 word = mine | (other << 16);
        int b = brow + quad*4 + r;
        size_t e = sbase + (size_t)(ktj*64 + b)*32 + kub + lcol;
        __hip_atomic_store((u32*)(Hbuf + e), word, __ATOMIC_RELAXED, __HIP_MEMORY_SCOPE_AGENT);
      }
    }
    // no drain, no flags, no pad stores: sentinel-free data is the ready signal
  }
}

// ---------------- FC + log_softmax ----------------
__global__ __launch_bounds__(256,2) void k_fc(
    const u16* __restrict__ Hbuf, const u16* __restrict__ Wfc,
    const float* __restrict__ biasfc, void* __restrict__ outv, const u32* __restrict__ dtf)
{
  __shared__ u16 As[64][128];
  __shared__ u16 Bst[64][128];
  const bool isf32 = (*dtf >= 8u);
  const int tid = threadIdx.x;
  const int r0 = blockIdx.x*64;
  const u32* Hu = (const u32*)Hbuf;
  const u32* Wu = (const u32*)Wfc;
  u32* Asu = (u32*)&As[0][0];
  u32* Bsu = (u32*)&Bst[0][0];
  const int w = tid>>6, lane = tid&63, quad = lane>>4, lcol = lane&15;
  f32x4 acc[4] = {};
  for (int ch=0; ch<5; ++ch) {
    __syncthreads();
    for (int e = tid; e < 4096; e += 256) {
      int rr = e>>6, cu = e&63;
      int r = r0 + rr, t = r>>6, b = r&63;
      int kk = ch*128 + cu*2;
      int part = (kk>=320), uu = kk - part*320;
      u32 v = 0;
      if (uu < 304) {
        size_t slot = part ? (size_t)(256 - t) : (size_t)(t + 1);
        v = Hu[(size_t)part*SLOTS*10240 + slot*10240 + ((size_t)(uu>>5)*64 + b)*16 + ((uu&31)>>1)];
      }
      Asu[e] = v;
    }
    for (int e = tid; e < 4096; e += 256) {
      int n = e>>6, cu = e&63;
      Bsu[e] = Wu[(size_t)n*320 + ch*64 + cu];
    }
    __syncthreads();
    #pragma unroll
    for (int kt=0; kt<4; ++kt) {
      bf16x8 a = *(const bf16x8*)&As[w*16+lcol][kt*32 + quad*8];
      #pragma unroll
      for (int nt=0; nt<4; ++nt) {
        bf16x8 bb = *(const bf16x8*)&Bst[nt*16+lcol][kt*32 + quad*8];
        acc[nt] = MFMA16(a, bb, acc[nt]);
      }
    }
  }
  float vals[4][4];
  #pragma unroll
  for (int nt=0; nt<4; ++nt) {
    int cc = nt*16 + lcol;
    float bia = biasfc[cc];
    #pragma unroll
    for (int r=0; r<4; ++r) vals[nt][r] = (cc < 50) ? (acc[nt][r] + bia) : -3.0e38f;
  }
  float lz[4];
  #pragma unroll
  for (int r=0; r<4; ++r) {
    float m = fmaxf(fmaxf(vals[0][r], vals[1][r]), fmaxf(vals[2][r], vals[3][r]));
    #pragma unroll
    for (int dd=1; dd<16; dd<<=1) m = fmaxf(m, __shfl_xor(m, dd, 64));
    float s = 0.f;
    #pragma unroll
    for (int nt=0; nt<4; ++nt) s += __builtin_amdgcn_exp2f((vals[nt][r]-m)*1.4426950408889634f);
    #pragma unroll
    for (int dd=1; dd<16; dd<<=1) s += __shfl_xor(s, dd, 64);
    lz[r] = m + __builtin_amdgcn_logf(s)*0.6931471805599453f;
  }
  #pragma unroll
  for (int nt=0; nt<4; ++nt) {
    int cc = nt*16 + lcol;
    if (cc < 50) {
      #pragma unroll
      for (int r=0; r<4; ++r) {
        int row = r0 + w*16 + quad*4 + r;
        int t = row>>6, b = row&63;
        size_t idx = ((size_t)b*256 + t)*50 + cc;
        float v = vals[nt][r] - lz[r];
        if (isf32) ((float*)outv)[idx] = v;
        else       ((u16*)outv)[idx] = f2bf(v);
      }
    }
  }
}

// ---------------- launch ----------------
extern "C" void kernel_launch(void* const* d_in, const int* in_sizes, int n_in,
                              void* d_out, int out_size, void* d_ws, size_t ws_size,
                              hipStream_t stream) {
  (void)in_sizes; (void)n_in; (void)out_size;
  if (ws_size < WS_NEED) return;

  const int* word_ids = (const int*)d_in[0];
  const int* char_ids = (const int*)d_in[1];
  const void* wemb   = d_in[2];
  const void* cemb   = d_in[3];
  const void* cWih   = d_in[4];
  const void* cWhh   = d_in[5];
  const void* cbih   = d_in[6];
  const void* cbhh   = d_in[7];
  const void* b0_Wih = d_in[8];
  const void* b0_Whh = d_in[9];
  const void* b0_bih = d_in[10];
  const void* b0_bhh = d_in[11];
  const void* b1_Wih = d_in[12];
  const void* b1_Whh = d_in[13];
  const void* b1_bih = d_in[14];
  const void* b1_bhh = d_in[15];
  const void* fcW    = d_in[16];
  const void* fcb    = d_in[17];

  char* ws = (char*)d_ws;
  u16*   xg   = (u16*)(ws + OFF_XG);
  u16*   H0   = (u16*)(ws + OFF_H0);
  u16*   H1   = (u16*)(ws + OFF_H1);
  u16*   cf   = (u16*)(ws + OFF_CF);
  u16*   W0p  = (u16*)(ws + OFF_W0);
  u16*   W1p  = (u16*)(ws + OFF_W1);
  u16*   Wfc  = (u16*)(ws + OFF_WFC);
  float* bia0 = (float*)(ws + OFF_B0);
  float* bia1 = (float*)(ws + OFF_B1);
  float* biaf = (float*)(ws + OFF_BFC);
  u32*   dtf  = (u32*)(ws + OFF_DT);

  // sentinel-fill H buffers, then zero the initial h slots (slot 0, both dirs, both layers)
  hipMemsetAsync(H0, 0xFF, SZ_HB, stream);
  hipMemsetAsync(H1, 0xFF, SZ_HB, stream);
  hipMemsetAsync(H0,                      0, (size_t)HSLOT*2, stream);
  hipMemsetAsync(H0 + (size_t)SLOTS*HSLOT, 0, (size_t)HSLOT*2, stream);
  hipMemsetAsync(H1,                      0, (size_t)HSLOT*2, stream);
  hipMemsetAsync(H1 + (size_t)SLOTS*HSLOT, 0, (size_t)HSLOT*2, stream);
  hipMemsetAsync(dtf, 0, 4, stream);

  k_detect<<<1, 256, 0, stream>>>((const u16*)wemb, dtf);
  k_prep<<<7780, 256, 0, stream>>>(b0_Wih, b0_bih, b0_bhh, b1_Wih, b1_bih, b1_bhh,
                                   fcW, fcb, W0p, W1p, Wfc, bia0, bia1, biaf, dtf);
  k_char<<<256, 256, 0, stream>>>(char_ids, cemb, cWih, cWhh, cbih, cbhh, cf, dtf);
  k_proj0<<<dim3(256,38), 256, 0, stream>>>(word_ids, wemb, cf, W0p, bia0, xg, dtf);
  k_scan<<<2*NWG, 256, 0, stream>>>(xg, b0_Whh, H0, dtf);
  k_proj1<<<dim3(256,38), 256, 0, stream>>>(H0, W1p, bia1, xg);
  k_scan<<<2*NWG, 256, 0, stream>>>(xg, b1_Whh, H1, dtf);
  k_fc<<<256, 256, 0, stream>>>(H1, Wfc, biaf, d_out, dtf);
}